// Round 6
// baseline (425.999 us; speedup 1.0000x reference)
//
#include <hip/hip_runtime.h>
#include <hip/hip_bf16.h>
#include <cstdint>

#define Bz 2
#define Tz 2048
#define Dz 1024
#define Hz 16
#define NR (Bz*Tz)   // 4096 rows

typedef __bf16 bf16;
typedef __bf16 bf16x8 __attribute__((ext_vector_type(8)));
typedef __bf16 bf16x4 __attribute__((ext_vector_type(4)));
typedef short  s16x4  __attribute__((ext_vector_type(4)));
typedef float  f32x4  __attribute__((ext_vector_type(4)));

typedef unsigned int u32as1 __attribute__((address_space(1)));
typedef unsigned int u32as3 __attribute__((address_space(3)));

__device__ __forceinline__ void gl2lds16(const void* gp, void* lp) {
    __builtin_amdgcn_global_load_lds((u32as1*)gp, (u32as3*)lp, 16, 0, 0);
}

// ---------------- transpose + f32->bf16 cast (+scale): W[K][N] -> WT[N][K] ----------------
__global__ void k_transpose_cvt(const float* __restrict__ W, bf16* __restrict__ WT,
                                int K, int N, float scale) {
    __shared__ float tile[32][33];
    const int n0 = blockIdx.x * 32, k0 = blockIdx.y * 32;
    const int tx = threadIdx.x, ty = threadIdx.y;   // (32,8)
#pragma unroll
    for (int i = 0; i < 4; i++)
        tile[ty + i*8][tx] = W[(size_t)(k0 + ty + i*8) * N + n0 + tx];
    __syncthreads();
#pragma unroll
    for (int i = 0; i < 4; i++)
        WT[(size_t)(n0 + ty + i*8) * K + k0 + tx] = (bf16)(tile[tx][ty + i*8] * scale);
}

// ---------------- V transpose: qkv V-third -> Vt[(b*16+h)*64 + v][Tz] ----------------
__global__ void k_vtrans(const bf16* __restrict__ qkv, bf16* __restrict__ Vt) {
    __shared__ bf16 tile[64][72];   // [t_local][v], padded
    const int t0 = blockIdx.x * 64;
    const int bh = blockIdx.y;
    const int b = bh >> 4, h = bh & 15;
    const int tid = threadIdx.x;
    const int tr = tid >> 3, c8 = (tid & 7) * 8;
    const bf16* src = qkv + (size_t)b * Tz * 3072 + 2048 + h * 64;
#pragma unroll
    for (int i = 0; i < 2; i++) {
        bf16x8 v = *(const bf16x8*)(src + (size_t)(t0 + i*32 + tr) * 3072 + c8);
        *(bf16x8*)&tile[i*32 + tr][c8] = v;
    }
    __syncthreads();
    bf16* dst = Vt + (size_t)bh * 64 * Tz + t0;
#pragma unroll
    for (int i = 0; i < 2; i++) {
        const int vr = i*32 + tr;
        bf16x8 o;
#pragma unroll
        for (int j = 0; j < 8; j++) o[j] = tile[c8 + j][vr];
        *(bf16x8*)(dst + (size_t)vr * Tz + c8) = o;
    }
}

// ---------------- LayerNorm (ddof=1 std, eps added to std) -> bf16 ----------------
__global__ void k_layernorm(const float* __restrict__ X, const float* __restrict__ gam,
                            const float* __restrict__ bet, bf16* __restrict__ out) {
    const int row = blockIdx.x, t = threadIdx.x;   // 256 threads, D=1024
    const float4 v = ((const float4*)(X + (size_t)row * Dz))[t];
    float s  = v.x + v.y + v.z + v.w;
    float ss = v.x*v.x + v.y*v.y + v.z*v.z + v.w*v.w;
#pragma unroll
    for (int o = 1; o < 64; o <<= 1) { s += __shfl_xor(s, o); ss += __shfl_xor(ss, o); }
    __shared__ float rs[4], rss[4];
    if ((t & 63) == 0) { rs[t >> 6] = s; rss[t >> 6] = ss; }
    __syncthreads();
    s  = rs[0] + rs[1] + rs[2] + rs[3];
    ss = rss[0] + rss[1] + rss[2] + rss[3];
    const float mean = s * (1.f / Dz);
    const float var  = fmaxf((ss - s * mean) * (1.f / (Dz - 1)), 0.f);
    const float inv  = 1.f / (sqrtf(var) + 1e-6f);
    const float4 gv = ((const float4*)gam)[t];
    const float4 bv = ((const float4*)bet)[t];
    bf16x4 o;
    o[0] = (bf16)((v.x - mean) * gv.x * inv + bv.x);
    o[1] = (bf16)((v.y - mean) * gv.y * inv + bv.y);
    o[2] = (bf16)((v.z - mean) * gv.z * inv + bv.z);
    o[3] = (bf16)((v.w - mean) * gv.w * inv + bv.w);
    *(bf16x4*)(out + (size_t)row * Dz + t * 4) = o;
}

// ---------------- generic bf16 GEMM: C[M][N] = A[M][K] * BT[N][K]^T ----------------
// 128x128 tile, BK=64. Split-K: gridDim.z = nsplit, each z computes a K-slice
// and writes bf16 partials to Pb[z][M][N] (reduced by k_reduce_*).
__global__ __launch_bounds__(256) void k_gemm(
    const bf16* __restrict__ A, const bf16* __restrict__ BT,
    int M, int N, int K,
    const float* __restrict__ bias, const float* __restrict__ resid,
    float* __restrict__ Cf, bf16* __restrict__ Cb, int act,
    bf16* __restrict__ Pb, int nsplit)
{
    __shared__ bf16 lA[128 * 64];
    __shared__ bf16 lB[128 * 64];
    const int tid = threadIdx.x;
    const int w = tid >> 6, lane = tid & 63;
    const int q = lane >> 4, l16 = lane & 15;
    const int m0 = blockIdx.y * 128, n0 = blockIdx.x * 128;
    const int wm = (w >> 1) * 64, wn = (w & 1) * 64;

    const int srow = lane >> 3;                 // 0..7
    const int skg  = (lane & 7) ^ srow;         // XOR-swizzled k-slot
    const bf16* Ab = A  + (size_t)(m0 + w * 32 + srow) * K + skg * 8;
    const bf16* Bb = BT + (size_t)(n0 + w * 32 + srow) * K + skg * 8;
    bf16* lAw = lA + w * 2048;
    bf16* lBw = lB + w * 2048;

    f32x4 acc[4][4] = {};

    const int kPer = K / nsplit;
    const int kBeg = blockIdx.z * kPer, kEnd = kBeg + kPer;
    for (int k0 = kBeg; k0 < kEnd; k0 += 64) {
#pragma unroll
        for (int i = 0; i < 4; i++) {
            gl2lds16(Ab + (size_t)i * 8 * K + k0, lAw + i * 512);
            gl2lds16(Bb + (size_t)i * 8 * K + k0, lBw + i * 512);
        }
        __syncthreads();
#pragma unroll
        for (int kh = 0; kh < 2; kh++) {
            const int sl = (((kh * 4 + q) ^ (l16 & 7)) * 8);
            bf16x8 af[4], bfr[4];
#pragma unroll
            for (int t = 0; t < 4; t++) {
                af[t]  = *(const bf16x8*)(lA + (wm + t * 16 + l16) * 64 + sl);
                bfr[t] = *(const bf16x8*)(lB + (wn + t * 16 + l16) * 64 + sl);
            }
#pragma unroll
            for (int i = 0; i < 4; i++)
#pragma unroll
                for (int j = 0; j < 4; j++)
                    acc[i][j] = __builtin_amdgcn_mfma_f32_16x16x32_bf16(
                        af[i], bfr[j], acc[i][j], 0, 0, 0);
        }
        __syncthreads();
    }

    if (nsplit > 1) {
        bf16* P = Pb + (size_t)blockIdx.z * M * N;
#pragma unroll
        for (int i = 0; i < 4; i++) {
            const int gr = m0 + wm + i * 16 + q * 4;
#pragma unroll
            for (int j = 0; j < 4; j++) {
                const int gc = n0 + wn + j * 16 + l16;
#pragma unroll
                for (int r = 0; r < 4; r++)
                    P[(size_t)(gr + r) * N + gc] = (bf16)acc[i][j][r];
            }
        }
        return;
    }

#pragma unroll
    for (int i = 0; i < 4; i++) {
        const int gr = m0 + wm + i * 16 + q * 4;
#pragma unroll
        for (int j = 0; j < 4; j++) {
            const int gc = n0 + wn + j * 16 + l16;
            const float bv = bias ? bias[gc] : 0.f;
#pragma unroll
            for (int r = 0; r < 4; r++) {
                float v = acc[i][j][r] + bv;
                if (act) v = 0.5f * v * (1.f + erff(v * 0.70710678118f));
                const size_t idx = (size_t)(gr + r) * N + gc;
                if (resid) v += resid[idx];
                if (Cf) Cf[idx] = v;
                else    Cb[idx] = (bf16)v;
            }
        }
    }
}

// ---------------- proj reduce (4 bf16 partials) + bias + resid -> y, then LN2 -> h2 ----------------
__global__ __launch_bounds__(256) void k_reduce_ln(
    const bf16* __restrict__ part, size_t MN,
    const float* __restrict__ bias, const float* __restrict__ resid,
    float* __restrict__ y,
    const float* __restrict__ gam, const float* __restrict__ bet,
    bf16* __restrict__ h2)
{
    const int row = blockIdx.x, t = threadIdx.x;
    const size_t i4 = (size_t)row * Dz + t * 4;
    float4 v = {0.f, 0.f, 0.f, 0.f};
#pragma unroll
    for (int s = 0; s < 4; s++) {
        const bf16x4 p = *(const bf16x4*)(part + s * MN + i4);
        v.x += (float)p[0]; v.y += (float)p[1]; v.z += (float)p[2]; v.w += (float)p[3];
    }
    const float4 bv = ((const float4*)bias)[t];
    const float4 rv = *(const float4*)(resid + i4);
    v.x += bv.x + rv.x; v.y += bv.y + rv.y; v.z += bv.z + rv.z; v.w += bv.w + rv.w;
    *(float4*)(y + i4) = v;

    float s  = v.x + v.y + v.z + v.w;
    float ss = v.x*v.x + v.y*v.y + v.z*v.z + v.w*v.w;
#pragma unroll
    for (int o = 1; o < 64; o <<= 1) { s += __shfl_xor(s, o); ss += __shfl_xor(ss, o); }
    __shared__ float rs[4], rss[4];
    if ((t & 63) == 0) { rs[t >> 6] = s; rss[t >> 6] = ss; }
    __syncthreads();
    s  = rs[0] + rs[1] + rs[2] + rs[3];
    ss = rss[0] + rss[1] + rss[2] + rss[3];
    const float mean = s * (1.f / Dz);
    const float var  = fmaxf((ss - s * mean) * (1.f / (Dz - 1)), 0.f);
    const float inv  = 1.f / (sqrtf(var) + 1e-6f);
    const float4 gv = ((const float4*)gam)[t];
    const float4 be = ((const float4*)bet)[t];
    bf16x4 o;
    o[0] = (bf16)((v.x - mean) * gv.x * inv + be.x);
    o[1] = (bf16)((v.y - mean) * gv.y * inv + be.y);
    o[2] = (bf16)((v.z - mean) * gv.z * inv + be.z);
    o[3] = (bf16)((v.w - mean) * gv.w * inv + be.w);
    *(bf16x4*)(h2 + i4) = o;
}

// ---------------- final reduce (4 bf16 partials) + bias + resid -> out (f32) ----------------
__global__ __launch_bounds__(256) void k_reduce_out(
    const bf16* __restrict__ part, size_t MN, int N,
    const float* __restrict__ bias, const float* __restrict__ resid,
    float* __restrict__ out)
{
    const size_t i4 = ((size_t)blockIdx.x * 256 + threadIdx.x) * 4;
    float4 v = {0.f, 0.f, 0.f, 0.f};
#pragma unroll
    for (int s = 0; s < 4; s++) {
        const bf16x4 p = *(const bf16x4*)(part + s * MN + i4);
        v.x += (float)p[0]; v.y += (float)p[1]; v.z += (float)p[2]; v.w += (float)p[3];
    }
    const int col = (int)(i4 % N);
    const float4 bv = *(const float4*)(bias + col);
    const float4 rv = *(const float4*)(resid + i4);
    v.x += bv.x + rv.x; v.y += bv.y + rv.y; v.z += bv.z + rv.z; v.w += bv.w + rv.w;
    *(float4*)(out + i4) = v;
}

// ---------------- flash attention v4: balanced causal pairing ----------------
__global__ __launch_bounds__(256) void k_attn(const bf16* __restrict__ qkv,
                                              const bf16* __restrict__ Vt,
                                              bf16* __restrict__ ctx)
{
    __shared__ __align__(16) char smem[34816];
    bf16* lK = (bf16*)smem;             // [128 rows][64 elems]
    bf16* lV = (bf16*)(smem + 16384);   // [64 rows][128 elems]
    f32x4* sAcc = (f32x4*)smem;         // [wq][vt][lane]  (aliases lK)
    float*  sM  = (float*)(smem + 32768);
    float*  sL  = (float*)(smem + 33792);

    const int tid = threadIdx.x, lane = tid & 63, w = tid >> 6;
    const int l16 = lane & 15, quad = lane >> 4;
    const int wq = w & 1, ws = w >> 1;
    const int pr = blockIdx.x;                   // pair index 0..31
    const int h = blockIdx.y, b = blockIdx.z;

    const bf16* Qp  = qkv + (size_t)b * Tz * 3072 + h * 64;
    const bf16* Kp  = Qp + 1024;
    const bf16* Vtp = Vt + (size_t)(b * Hz + h) * 64 * Tz;

    const int krow  = tid >> 3;
    const int kslot = (tid & 7) ^ (krow & 7);
    const bf16* Kg = Kp + (size_t)krow * 3072 + kslot * 8;
    const int vrow  = tid >> 4;
    const int vslot = (tid & 15) ^ (vrow & 7);
    const bf16* Vg = Vtp + (size_t)vrow * Tz + vslot * 8;

#pragma unroll
    for (int ti = 0; ti < 2; ti++) {
        const int t = ti ? (63 - pr) : pr;       // 32-row q-tile index
        const int q0 = t * 32 + wq * 16;         // this wave's 16 q rows

        bf16x8 qf[2];
#pragma unroll
        for (int kh = 0; kh < 2; kh++)
            qf[kh] = *(const bf16x8*)(Qp + (size_t)(q0 + l16) * 3072 + kh*32 + quad*8);

        f32x4 acc[4] = {};
        float m = -1e30f, l = 0.f;

        const int keyEnd = t * 32 + 32;
        for (int ktB = 0; ktB < keyEnd; ktB += 128) {
            __syncthreads();                     // staging vs prior compute/merge
#pragma unroll
            for (int s = 0; s < 4; s++) {
                gl2lds16(Kg + (size_t)(ktB + s * 32) * 3072, lK + s * 2048 + w * 512);
                gl2lds16(Vg + (size_t)s * 16 * Tz + ktB,     lV + s * 2048 + w * 512);
            }
            __syncthreads();

            const int kt = ktB + ws * 64;
            if (kt <= q0 + 15) {                 // wave-uniform causal skip
                f32x4 sv[4];
                const int sw = l16 & 7;
#pragma unroll
                for (int c = 0; c < 4; c++) {
                    const int R = ws * 64 + c * 16 + l16;
                    bf16x8 kf0 = *(const bf16x8*)(lK + R * 64 + ((quad     ^ sw) * 8));
                    bf16x8 kf1 = *(const bf16x8*)(lK + R * 64 + (((4+quad) ^ sw) * 8));
                    f32x4 z = {0.f, 0.f, 0.f, 0.f};
                    z = __builtin_amdgcn_mfma_f32_16x16x32_bf16(kf0, qf[0], z, 0, 0, 0);
                    z = __builtin_amdgcn_mfma_f32_16x16x32_bf16(kf1, qf[1], z, 0, 0, 0);
                    sv[c] = z;
                }
                if (kt + 63 > q0) {              // mask only on diagonal tiles
#pragma unroll
                    for (int c = 0; c < 4; c++)
#pragma unroll
                        for (int r = 0; r < 4; r++)
                            if (kt + c*16 + quad*4 + r > q0 + l16) sv[c][r] = -1e30f;
                }
                float t0 = fmaxf(fmaxf(sv[0][0], sv[0][1]), fmaxf(sv[0][2], sv[0][3]));
                float t1 = fmaxf(fmaxf(sv[1][0], sv[1][1]), fmaxf(sv[1][2], sv[1][3]));
                float t2 = fmaxf(fmaxf(sv[2][0], sv[2][1]), fmaxf(sv[2][2], sv[2][3]));
                float t3 = fmaxf(fmaxf(sv[3][0], sv[3][1]), fmaxf(sv[3][2], sv[3][3]));
                float tm = fmaxf(fmaxf(t0, t1), fmaxf(t2, t3));
                tm = fmaxf(tm, __shfl_xor(tm, 16));
                tm = fmaxf(tm, __shfl_xor(tm, 32));
                if (__any(tm > m)) {
                    const float mn = fmaxf(m, tm);
                    const float a  = __expf(m - mn);
                    m = mn;
                    l *= a;
#pragma unroll
                    for (int vt = 0; vt < 4; vt++)
#pragma unroll
                        for (int r = 0; r < 4; r++) acc[vt][r] *= a;
                }
                float ts = 0.f;
#pragma unroll
                for (int c = 0; c < 4; c++) {
                    s16x4 vf[4];
                    const int gslot = ws * 8 + c * 2 + (quad >> 1);
#pragma unroll
                    for (int vt = 0; vt < 4; vt++) {
                        const int Rv = vt * 16 + l16;
                        vf[vt] = *(const s16x4*)(lV + Rv * 128 + ((gslot ^ (Rv & 7)) * 8)
                                                 + (quad & 1) * 4);
                    }
                    bf16x4 tb;
#pragma unroll
                    for (int r = 0; r < 4; r++) {
                        const float p = __expf(sv[c][r] - m);
                        ts += p;
                        tb[r] = (bf16)p;
                    }
                    const s16x4 pb = __builtin_bit_cast(s16x4, tb);
#pragma unroll
                    for (int vt = 0; vt < 4; vt++)
                        acc[vt] = __builtin_amdgcn_mfma_f32_16x16x16bf16_1k(
                            vf[vt], pb, acc[vt], 0, 0, 0);
                }
                ts += __shfl_xor(ts, 16);
                ts += __shfl_xor(ts, 32);
                l += ts;
            }
        }

        // merge ws halves (LDS aliased onto staging buffers)
        __syncthreads();
        if (ws == 1) {
            sM[wq * 64 + lane] = m;
            sL[wq * 64 + lane] = l;
#pragma unroll
            for (int vt = 0; vt < 4; vt++)
                sAcc[(wq * 4 + vt) * 64 + lane] = acc[vt];
        }
        __syncthreads();
        if (ws == 0) {
            const float m1 = sM[wq * 64 + lane], l1 = sL[wq * 64 + lane];
            const float M  = fmaxf(m, m1);
            const float a0 = __expf(m - M), a1 = __expf(m1 - M);
            const float inv = 1.f / (l * a0 + l1 * a1);
#pragma unroll
            for (int vt = 0; vt < 4; vt++) {
                const f32x4 o1 = sAcc[(wq * 4 + vt) * 64 + lane];
                bf16x4 o;
#pragma unroll
                for (int r = 0; r < 4; r++)
                    o[r] = (bf16)((acc[vt][r] * a0 + o1[r] * a1) * inv);
                *(bf16x4*)(ctx + (size_t)(b * Tz + q0 + l16) * 1024
                           + h * 64 + vt * 16 + quad * 4) = o;
            }
        }
    }
}

// ---------------- driver ----------------
extern "C" void kernel_launch(void* const* d_in, const int* in_sizes, int n_in,
                              void* d_out, int out_size, void* d_ws, size_t ws_size,
                              hipStream_t stream)
{
    const float* x     = (const float*)d_in[0];
    const float* w_q   = (const float*)d_in[1];
    const float* w_k   = (const float*)d_in[2];
    const float* w_v   = (const float*)d_in[3];
    const float* w_o   = (const float*)d_in[4];
    const float* b_o   = (const float*)d_in[5];
    const float* w_fc1 = (const float*)d_in[6];
    const float* b_fc1 = (const float*)d_in[7];
    const float* w_fc2 = (const float*)d_in[8];
    const float* b_fc2 = (const float*)d_in[9];
    const float* ln1_g = (const float*)d_in[10];
    const float* ln1_b = (const float*)d_in[11];
    const float* ln2_g = (const float*)d_in[12];
    const float* ln2_b = (const float*)d_in[13];
    float* out = (float*)d_out;

    char* p = (char*)d_ws;
    bf16* wqkvT = (bf16*)p; p += (size_t)3072 * 1024 * 2;
    bf16* woT   = (bf16*)p; p += (size_t)1024 * 1024 * 2;
    bf16* wfc1T = (bf16*)p; p += (size_t)4096 * 1024 * 2;
    bf16* wfc2T = (bf16*)p; p += (size_t)1024 * 4096 * 2;
    bf16* h1    = (bf16*)p; p += (size_t)NR * 1024 * 2;   // reused: Vt, then FC2 partials
    bf16* qkv   = (bf16*)p; p += (size_t)NR * 3072 * 2;   // FC2 partials tail
    bf16* ctx   = (bf16*)p; p += (size_t)NR * 1024 * 2;
    float* y    = (float*)p; p += (size_t)NR * 1024 * 4;
    bf16* h2    = (bf16*)p; p += (size_t)NR * 1024 * 2;
    bf16* g     = (bf16*)p; p += (size_t)NR * 4096 * 2;   // reused: proj partials
    bf16* Vt    = h1;
    bf16* projPart = g;     // 4 * NR*1024*2 B = 33.55 MB == sizeof(g)
    bf16* fc2Part  = h1;    // 33.55 MB == sizeof(h1)+sizeof(qkv)
    const size_t MN = (size_t)NR * 1024;

    const dim3 tb(32, 8);
    k_transpose_cvt<<<dim3(32, 32),  tb, 0, stream>>>(w_q,   wqkvT,             1024, 1024, 0.125f);
    k_transpose_cvt<<<dim3(32, 32),  tb, 0, stream>>>(w_k,   wqkvT + 1024*1024, 1024, 1024, 1.f);
    k_transpose_cvt<<<dim3(32, 32),  tb, 0, stream>>>(w_v,   wqkvT + 2048*1024, 1024, 1024, 1.f);
    k_transpose_cvt<<<dim3(32, 32),  tb, 0, stream>>>(w_o,   woT,               1024, 1024, 1.f);
    k_transpose_cvt<<<dim3(128, 32), tb, 0, stream>>>(w_fc1, wfc1T,             1024, 4096, 1.f);
    k_transpose_cvt<<<dim3(32, 128), tb, 0, stream>>>(w_fc2, wfc2T,             4096, 1024, 1.f);

    k_layernorm<<<NR, 256, 0, stream>>>(x, ln1_g, ln1_b, h1);
    k_gemm<<<dim3(3072/128, NR/128), 256, 0, stream>>>(h1, wqkvT, NR, 3072, 1024,
                                                       nullptr, nullptr, nullptr, qkv, 0,
                                                       nullptr, 1);
    k_vtrans<<<dim3(Tz/64, Bz*Hz), 256, 0, stream>>>(qkv, Vt);
    k_attn<<<dim3(32, Hz, Bz), 256, 0, stream>>>(qkv, Vt, ctx);

    // out-proj: split-K=4, bf16 partials in g; fused reduce + LN2 -> y, h2
    k_gemm<<<dim3(1024/128, NR/128, 4), 256, 0, stream>>>(ctx, woT, NR, 1024, 1024,
                                                          nullptr, nullptr, nullptr, nullptr, 0,
                                                          projPart, 4);
    k_reduce_ln<<<NR, 256, 0, stream>>>(projPart, MN, b_o, x, y, ln2_g, ln2_b, h2);

    k_gemm<<<dim3(4096/128, NR/128), 256, 0, stream>>>(h2, wfc1T, NR, 4096, 1024,
                                                       b_fc1, nullptr, nullptr, g, 1,
                                                       nullptr, 1);
    // FC2: split-K=4, bf16 partials in h1+qkv; reduce fuses +b_fc2 +y -> out (f32)
    k_gemm<<<dim3(1024/128, NR/128, 4), 256, 0, stream>>>(g, wfc2T, NR, 1024, 4096,
                                                          nullptr, nullptr, nullptr, nullptr, 0,
                                                          fc2Part, 4);
    k_reduce_out<<<MN / 1024, 256, 0, stream>>>(fc2Part, MN, 1024, b_fc2, y, out);
    (void)in_sizes; (void)n_in; (void)out_size; (void)ws_size;
}

// Round 7
// 406.850 us; speedup vs baseline: 1.0471x; 1.0471x over previous
//
#include <hip/hip_runtime.h>
#include <hip/hip_bf16.h>
#include <cstdint>

#define Bz 2
#define Tz 2048
#define Dz 1024
#define Hz 16
#define NR (Bz*Tz)   // 4096 rows

typedef __bf16 bf16;
typedef __bf16 bf16x8 __attribute__((ext_vector_type(8)));
typedef __bf16 bf16x4 __attribute__((ext_vector_type(4)));
typedef short  s16x4  __attribute__((ext_vector_type(4)));
typedef float  f32x4  __attribute__((ext_vector_type(4)));

typedef unsigned int u32as1 __attribute__((address_space(1)));
typedef unsigned int u32as3 __attribute__((address_space(3)));

__device__ __forceinline__ void gl2lds16(const void* gp, void* lp) {
    __builtin_amdgcn_global_load_lds((u32as1*)gp, (u32as3*)lp, 16, 0, 0);
}

// ---------------- transpose + f32->bf16 cast (+scale): W[K][N] -> WT[N][K] ----------------
__global__ void k_transpose_cvt(const float* __restrict__ W, bf16* __restrict__ WT,
                                int K, int N, float scale) {
    __shared__ float tile[32][33];
    const int n0 = blockIdx.x * 32, k0 = blockIdx.y * 32;
    const int tx = threadIdx.x, ty = threadIdx.y;   // (32,8)
#pragma unroll
    for (int i = 0; i < 4; i++)
        tile[ty + i*8][tx] = W[(size_t)(k0 + ty + i*8) * N + n0 + tx];
    __syncthreads();
#pragma unroll
    for (int i = 0; i < 4; i++)
        WT[(size_t)(n0 + ty + i*8) * K + k0 + tx] = (bf16)(tile[tx][ty + i*8] * scale);
}

// ---------------- V transpose: qkv V-third -> Vt[(b*16+h)*64 + v][Tz] ----------------
__global__ void k_vtrans(const bf16* __restrict__ qkv, bf16* __restrict__ Vt) {
    __shared__ bf16 tile[64][72];   // [t_local][v], padded
    const int t0 = blockIdx.x * 64;
    const int bh = blockIdx.y;
    const int b = bh >> 4, h = bh & 15;
    const int tid = threadIdx.x;
    const int tr = tid >> 3, c8 = (tid & 7) * 8;
    const bf16* src = qkv + (size_t)b * Tz * 3072 + 2048 + h * 64;
#pragma unroll
    for (int i = 0; i < 2; i++) {
        bf16x8 v = *(const bf16x8*)(src + (size_t)(t0 + i*32 + tr) * 3072 + c8);
        *(bf16x8*)&tile[i*32 + tr][c8] = v;
    }
    __syncthreads();
    bf16* dst = Vt + (size_t)bh * 64 * Tz + t0;
#pragma unroll
    for (int i = 0; i < 2; i++) {
        const int vr = i*32 + tr;
        bf16x8 o;
#pragma unroll
        for (int j = 0; j < 8; j++) o[j] = tile[c8 + j][vr];
        *(bf16x8*)(dst + (size_t)vr * Tz + c8) = o;
    }
}

// ---------------- LayerNorm (ddof=1 std, eps added to std) -> bf16 ----------------
__global__ void k_layernorm(const float* __restrict__ X, const float* __restrict__ gam,
                            const float* __restrict__ bet, bf16* __restrict__ out) {
    const int row = blockIdx.x, t = threadIdx.x;   // 256 threads, D=1024
    const float4 v = ((const float4*)(X + (size_t)row * Dz))[t];
    float s  = v.x + v.y + v.z + v.w;
    float ss = v.x*v.x + v.y*v.y + v.z*v.z + v.w*v.w;
#pragma unroll
    for (int o = 1; o < 64; o <<= 1) { s += __shfl_xor(s, o); ss += __shfl_xor(ss, o); }
    __shared__ float rs[4], rss[4];
    if ((t & 63) == 0) { rs[t >> 6] = s; rss[t >> 6] = ss; }
    __syncthreads();
    s  = rs[0] + rs[1] + rs[2] + rs[3];
    ss = rss[0] + rss[1] + rss[2] + rss[3];
    const float mean = s * (1.f / Dz);
    const float var  = fmaxf((ss - s * mean) * (1.f / (Dz - 1)), 0.f);
    const float inv  = 1.f / (sqrtf(var) + 1e-6f);
    const float4 gv = ((const float4*)gam)[t];
    const float4 bv = ((const float4*)bet)[t];
    bf16x4 o;
    o[0] = (bf16)((v.x - mean) * gv.x * inv + bv.x);
    o[1] = (bf16)((v.y - mean) * gv.y * inv + bv.y);
    o[2] = (bf16)((v.z - mean) * gv.z * inv + bv.z);
    o[3] = (bf16)((v.w - mean) * gv.w * inv + bv.w);
    *(bf16x4*)(out + (size_t)row * Dz + t * 4) = o;
}

// ---------------- generic bf16 GEMM, double-buffered K-loop ----------------
// C[M][N] = A[M][K] * BT[N][K]^T. 128x128 tile, BK=64, 2x32KB LDS buffers.
// Raw s_barrier + manual vmcnt(8): next tile's global_load_lds stay in flight
// across the barriers (never drain to 0 mid-loop) — AITER-style pipelining.
// Split-K: gridDim.z = nsplit, f32 partials to Pf[z][M][N].
__global__ __launch_bounds__(256) void k_gemm(
    const bf16* __restrict__ A, const bf16* __restrict__ BT,
    int M, int N, int K,
    const float* __restrict__ bias, const float* __restrict__ resid,
    float* __restrict__ Cf, bf16* __restrict__ Cb, int act,
    float* __restrict__ Pf, int nsplit)
{
    __shared__ bf16 lA[2][128 * 64];
    __shared__ bf16 lB[2][128 * 64];
    const int tid = threadIdx.x;
    const int w = tid >> 6, lane = tid & 63;
    const int q = lane >> 4, l16 = lane & 15;
    const int m0 = blockIdx.y * 128, n0 = blockIdx.x * 128;
    const int wm = (w >> 1) * 64, wn = (w & 1) * 64;

    const int srow = lane >> 3;                 // 0..7
    const int skg  = (lane & 7) ^ srow;         // XOR-swizzled k-slot
    const bf16* Ab = A  + (size_t)(m0 + w * 32 + srow) * K + skg * 8;
    const bf16* Bb = BT + (size_t)(n0 + w * 32 + srow) * K + skg * 8;

    f32x4 acc[4][4] = {};

    const int kPer  = K / nsplit;
    const int kBeg  = blockIdx.z * kPer;
    const int iters = kPer >> 6;

    // prologue: stage buf0
#pragma unroll
    for (int i = 0; i < 4; i++) {
        gl2lds16(Ab + (size_t)i * 8 * K + kBeg, &lA[0][0] + w * 2048 + i * 512);
        gl2lds16(Bb + (size_t)i * 8 * K + kBeg, &lB[0][0] + w * 2048 + i * 512);
    }

    for (int it = 0; it < iters; ++it) {
        const int cur = it & 1;
        // close previous consume of buf[cur^1] for ALL waves before overwriting it
        asm volatile("s_barrier" ::: "memory");
        if (it + 1 < iters) {
            const int k0 = kBeg + (it + 1) * 64;
#pragma unroll
            for (int i = 0; i < 4; i++) {
                gl2lds16(Ab + (size_t)i * 8 * K + k0, &lA[cur ^ 1][0] + w * 2048 + i * 512);
                gl2lds16(Bb + (size_t)i * 8 * K + k0, &lB[cur ^ 1][0] + w * 2048 + i * 512);
            }
            asm volatile("s_waitcnt vmcnt(8)" ::: "memory");   // own buf[cur] loads landed
        } else {
            asm volatile("s_waitcnt vmcnt(0)" ::: "memory");
        }
        asm volatile("s_barrier" ::: "memory");                // everyone's buf[cur] landed

        const bf16* lAc = lA[cur];
        const bf16* lBc = lB[cur];
#pragma unroll
        for (int kh = 0; kh < 2; kh++) {
            const int sl = (((kh * 4 + q) ^ (l16 & 7)) * 8);
            bf16x8 af[4], bfr[4];
#pragma unroll
            for (int t = 0; t < 4; t++) {
                af[t]  = *(const bf16x8*)(lAc + (wm + t * 16 + l16) * 64 + sl);
                bfr[t] = *(const bf16x8*)(lBc + (wn + t * 16 + l16) * 64 + sl);
            }
#pragma unroll
            for (int i = 0; i < 4; i++)
#pragma unroll
                for (int j = 0; j < 4; j++)
                    acc[i][j] = __builtin_amdgcn_mfma_f32_16x16x32_bf16(
                        af[i], bfr[j], acc[i][j], 0, 0, 0);
        }
    }

    if (nsplit > 1) {
        float* P = Pf + (size_t)blockIdx.z * M * N;
#pragma unroll
        for (int i = 0; i < 4; i++) {
            const int gr = m0 + wm + i * 16 + q * 4;
#pragma unroll
            for (int j = 0; j < 4; j++) {
                const int gc = n0 + wn + j * 16 + l16;
#pragma unroll
                for (int r = 0; r < 4; r++)
                    P[(size_t)(gr + r) * N + gc] = acc[i][j][r];
            }
        }
        return;
    }

#pragma unroll
    for (int i = 0; i < 4; i++) {
        const int gr = m0 + wm + i * 16 + q * 4;
#pragma unroll
        for (int j = 0; j < 4; j++) {
            const int gc = n0 + wn + j * 16 + l16;
            const float bv = bias ? bias[gc] : 0.f;
#pragma unroll
            for (int r = 0; r < 4; r++) {
                float v = acc[i][j][r] + bv;
                if (act) v = 0.5f * v * (1.f + erff(v * 0.70710678118f));
                const size_t idx = (size_t)(gr + r) * N + gc;
                if (resid) v += resid[idx];
                if (Cf) Cf[idx] = v;
                else    Cb[idx] = (bf16)v;
            }
        }
    }
}

// ---------------- proj reduce (2 f32 partials) + bias + resid -> y, then LN2 -> h2 ----------------
__global__ __launch_bounds__(256) void k_reduce_ln(
    const float* __restrict__ part, size_t MN,
    const float* __restrict__ bias, const float* __restrict__ resid,
    float* __restrict__ y,
    const float* __restrict__ gam, const float* __restrict__ bet,
    bf16* __restrict__ h2)
{
    const int row = blockIdx.x, t = threadIdx.x;
    const size_t i4 = (size_t)row * Dz + t * 4;
    float4 v = *(const float4*)(part + i4);
    const float4 p1 = *(const float4*)(part + MN + i4);
    const float4 bv = ((const float4*)bias)[t];
    const float4 rv = *(const float4*)(resid + i4);
    v.x += p1.x + bv.x + rv.x; v.y += p1.y + bv.y + rv.y;
    v.z += p1.z + bv.z + rv.z; v.w += p1.w + bv.w + rv.w;
    *(float4*)(y + i4) = v;

    float s  = v.x + v.y + v.z + v.w;
    float ss = v.x*v.x + v.y*v.y + v.z*v.z + v.w*v.w;
#pragma unroll
    for (int o = 1; o < 64; o <<= 1) { s += __shfl_xor(s, o); ss += __shfl_xor(ss, o); }
    __shared__ float rs[4], rss[4];
    if ((t & 63) == 0) { rs[t >> 6] = s; rss[t >> 6] = ss; }
    __syncthreads();
    s  = rs[0] + rs[1] + rs[2] + rs[3];
    ss = rss[0] + rss[1] + rss[2] + rss[3];
    const float mean = s * (1.f / Dz);
    const float var  = fmaxf((ss - s * mean) * (1.f / (Dz - 1)), 0.f);
    const float inv  = 1.f / (sqrtf(var) + 1e-6f);
    const float4 gv = ((const float4*)gam)[t];
    const float4 be = ((const float4*)bet)[t];
    bf16x4 o;
    o[0] = (bf16)((v.x - mean) * gv.x * inv + be.x);
    o[1] = (bf16)((v.y - mean) * gv.y * inv + be.y);
    o[2] = (bf16)((v.z - mean) * gv.z * inv + be.z);
    o[3] = (bf16)((v.w - mean) * gv.w * inv + be.w);
    *(bf16x4*)(h2 + i4) = o;
}

// ---------------- final reduce (2 f32 partials) + bias + resid -> out (f32) ----------------
__global__ __launch_bounds__(256) void k_reduce_out(
    const float* __restrict__ part, size_t MN, int N,
    const float* __restrict__ bias, const float* __restrict__ resid,
    float* __restrict__ out)
{
    const size_t i4 = ((size_t)blockIdx.x * 256 + threadIdx.x) * 4;
    float4 v = *(const float4*)(part + i4);
    const float4 p1 = *(const float4*)(part + MN + i4);
    const int col = (int)(i4 % N);
    const float4 bv = *(const float4*)(bias + col);
    const float4 rv = *(const float4*)(resid + i4);
    v.x += p1.x + bv.x + rv.x; v.y += p1.y + bv.y + rv.y;
    v.z += p1.z + bv.z + rv.z; v.w += p1.w + bv.w + rv.w;
    *(float4*)(out + i4) = v;
}

// ---------------- flash attention v4: balanced causal pairing ----------------
__global__ __launch_bounds__(256) void k_attn(const bf16* __restrict__ qkv,
                                              const bf16* __restrict__ Vt,
                                              bf16* __restrict__ ctx)
{
    __shared__ __align__(16) char smem[34816];
    bf16* lK = (bf16*)smem;             // [128 rows][64 elems]
    bf16* lV = (bf16*)(smem + 16384);   // [64 rows][128 elems]
    f32x4* sAcc = (f32x4*)smem;         // [wq][vt][lane]  (aliases lK)
    float*  sM  = (float*)(smem + 32768);
    float*  sL  = (float*)(smem + 33792);

    const int tid = threadIdx.x, lane = tid & 63, w = tid >> 6;
    const int l16 = lane & 15, quad = lane >> 4;
    const int wq = w & 1, ws = w >> 1;
    const int pr = blockIdx.x;                   // pair index 0..31
    const int h = blockIdx.y, b = blockIdx.z;

    const bf16* Qp  = qkv + (size_t)b * Tz * 3072 + h * 64;
    const bf16* Kp  = Qp + 1024;
    const bf16* Vtp = Vt + (size_t)(b * Hz + h) * 64 * Tz;

    const int krow  = tid >> 3;
    const int kslot = (tid & 7) ^ (krow & 7);
    const bf16* Kg = Kp + (size_t)krow * 3072 + kslot * 8;
    const int vrow  = tid >> 4;
    const int vslot = (tid & 15) ^ (vrow & 7);
    const bf16* Vg = Vtp + (size_t)vrow * Tz + vslot * 8;

#pragma unroll
    for (int ti = 0; ti < 2; ti++) {
        const int t = ti ? (63 - pr) : pr;       // 32-row q-tile index
        const int q0 = t * 32 + wq * 16;         // this wave's 16 q rows

        bf16x8 qf[2];
#pragma unroll
        for (int kh = 0; kh < 2; kh++)
            qf[kh] = *(const bf16x8*)(Qp + (size_t)(q0 + l16) * 3072 + kh*32 + quad*8);

        f32x4 acc[4] = {};
        float m = -1e30f, l = 0.f;

        const int keyEnd = t * 32 + 32;
        for (int ktB = 0; ktB < keyEnd; ktB += 128) {
            __syncthreads();                     // staging vs prior compute/merge
#pragma unroll
            for (int s = 0; s < 4; s++) {
                gl2lds16(Kg + (size_t)(ktB + s * 32) * 3072, lK + s * 2048 + w * 512);
                gl2lds16(Vg + (size_t)s * 16 * Tz + ktB,     lV + s * 2048 + w * 512);
            }
            __syncthreads();

            const int kt = ktB + ws * 64;
            if (kt <= q0 + 15) {                 // wave-uniform causal skip
                f32x4 sv[4];
                const int sw = l16 & 7;
#pragma unroll
                for (int c = 0; c < 4; c++) {
                    const int R = ws * 64 + c * 16 + l16;
                    bf16x8 kf0 = *(const bf16x8*)(lK + R * 64 + ((quad     ^ sw) * 8));
                    bf16x8 kf1 = *(const bf16x8*)(lK + R * 64 + (((4+quad) ^ sw) * 8));
                    f32x4 z = {0.f, 0.f, 0.f, 0.f};
                    z = __builtin_amdgcn_mfma_f32_16x16x32_bf16(kf0, qf[0], z, 0, 0, 0);
                    z = __builtin_amdgcn_mfma_f32_16x16x32_bf16(kf1, qf[1], z, 0, 0, 0);
                    sv[c] = z;
                }
                if (kt + 63 > q0) {              // mask only on diagonal tiles
#pragma unroll
                    for (int c = 0; c < 4; c++)
#pragma unroll
                        for (int r = 0; r < 4; r++)
                            if (kt + c*16 + quad*4 + r > q0 + l16) sv[c][r] = -1e30f;
                }
                float t0 = fmaxf(fmaxf(sv[0][0], sv[0][1]), fmaxf(sv[0][2], sv[0][3]));
                float t1 = fmaxf(fmaxf(sv[1][0], sv[1][1]), fmaxf(sv[1][2], sv[1][3]));
                float t2 = fmaxf(fmaxf(sv[2][0], sv[2][1]), fmaxf(sv[2][2], sv[2][3]));
                float t3 = fmaxf(fmaxf(sv[3][0], sv[3][1]), fmaxf(sv[3][2], sv[3][3]));
                float tm = fmaxf(fmaxf(t0, t1), fmaxf(t2, t3));
                tm = fmaxf(tm, __shfl_xor(tm, 16));
                tm = fmaxf(tm, __shfl_xor(tm, 32));
                if (__any(tm > m)) {
                    const float mn = fmaxf(m, tm);
                    const float a  = __expf(m - mn);
                    m = mn;
                    l *= a;
#pragma unroll
                    for (int vt = 0; vt < 4; vt++)
#pragma unroll
                        for (int r = 0; r < 4; r++) acc[vt][r] *= a;
                }
                float ts = 0.f;
#pragma unroll
                for (int c = 0; c < 4; c++) {
                    s16x4 vf[4];
                    const int gslot = ws * 8 + c * 2 + (quad >> 1);
#pragma unroll
                    for (int vt = 0; vt < 4; vt++) {
                        const int Rv = vt * 16 + l16;
                        vf[vt] = *(const s16x4*)(lV + Rv * 128 + ((gslot ^ (Rv & 7)) * 8)
                                                 + (quad & 1) * 4);
                    }
                    bf16x4 tb;
#pragma unroll
                    for (int r = 0; r < 4; r++) {
                        const float p = __expf(sv[c][r] - m);
                        ts += p;
                        tb[r] = (bf16)p;
                    }
                    const s16x4 pb = __builtin_bit_cast(s16x4, tb);
#pragma unroll
                    for (int vt = 0; vt < 4; vt++)
                        acc[vt] = __builtin_amdgcn_mfma_f32_16x16x16bf16_1k(
                            vf[vt], pb, acc[vt], 0, 0, 0);
                }
                ts += __shfl_xor(ts, 16);
                ts += __shfl_xor(ts, 32);
                l += ts;
            }
        }

        // merge ws halves (LDS aliased onto staging buffers)
        __syncthreads();
        if (ws == 1) {
            sM[wq * 64 + lane] = m;
            sL[wq * 64 + lane] = l;
#pragma unroll
            for (int vt = 0; vt < 4; vt++)
                sAcc[(wq * 4 + vt) * 64 + lane] = acc[vt];
        }
        __syncthreads();
        if (ws == 0) {
            const float m1 = sM[wq * 64 + lane], l1 = sL[wq * 64 + lane];
            const float M  = fmaxf(m, m1);
            const float a0 = __expf(m - M), a1 = __expf(m1 - M);
            const float inv = 1.f / (l * a0 + l1 * a1);
#pragma unroll
            for (int vt = 0; vt < 4; vt++) {
                const f32x4 o1 = sAcc[(wq * 4 + vt) * 64 + lane];
                bf16x4 o;
#pragma unroll
                for (int r = 0; r < 4; r++)
                    o[r] = (bf16)((acc[vt][r] * a0 + o1[r] * a1) * inv);
                *(bf16x4*)(ctx + (size_t)(b * Tz + q0 + l16) * 1024
                           + h * 64 + vt * 16 + quad * 4) = o;
            }
        }
    }
}

// ---------------- driver ----------------
extern "C" void kernel_launch(void* const* d_in, const int* in_sizes, int n_in,
                              void* d_out, int out_size, void* d_ws, size_t ws_size,
                              hipStream_t stream)
{
    const float* x     = (const float*)d_in[0];
    const float* w_q   = (const float*)d_in[1];
    const float* w_k   = (const float*)d_in[2];
    const float* w_v   = (const float*)d_in[3];
    const float* w_o   = (const float*)d_in[4];
    const float* b_o   = (const float*)d_in[5];
    const float* w_fc1 = (const float*)d_in[6];
    const float* b_fc1 = (const float*)d_in[7];
    const float* w_fc2 = (const float*)d_in[8];
    const float* b_fc2 = (const float*)d_in[9];
    const float* ln1_g = (const float*)d_in[10];
    const float* ln1_b = (const float*)d_in[11];
    const float* ln2_g = (const float*)d_in[12];
    const float* ln2_b = (const float*)d_in[13];
    float* out = (float*)d_out;

    char* p = (char*)d_ws;
    bf16* wqkvT = (bf16*)p; p += (size_t)3072 * 1024 * 2;
    bf16* woT   = (bf16*)p; p += (size_t)1024 * 1024 * 2;
    bf16* wfc1T = (bf16*)p; p += (size_t)4096 * 1024 * 2;
    bf16* wfc2T = (bf16*)p; p += (size_t)1024 * 4096 * 2;
    bf16* h1    = (bf16*)p; p += (size_t)NR * 1024 * 2;   // reused: Vt, then FC2 partials
    bf16* qkv   = (bf16*)p; p += (size_t)NR * 3072 * 2;   // FC2 partials tail
    bf16* ctx   = (bf16*)p; p += (size_t)NR * 1024 * 2;
    float* y    = (float*)p; p += (size_t)NR * 1024 * 4;
    bf16* h2    = (bf16*)p; p += (size_t)NR * 1024 * 2;
    bf16* g     = (bf16*)p; p += (size_t)NR * 4096 * 2;   // reused: proj partials
    bf16* Vt    = h1;
    float* projPart = (float*)g;    // 2 * NR*1024*4 B = 33.55 MB == sizeof(g)
    float* fc2Part  = (float*)h1;   // 33.55 MB == sizeof(h1)+sizeof(qkv)
    const size_t MN = (size_t)NR * 1024;

    const dim3 tb(32, 8);
    k_transpose_cvt<<<dim3(32, 32),  tb, 0, stream>>>(w_q,   wqkvT,             1024, 1024, 0.125f);
    k_transpose_cvt<<<dim3(32, 32),  tb, 0, stream>>>(w_k,   wqkvT + 1024*1024, 1024, 1024, 1.f);
    k_transpose_cvt<<<dim3(32, 32),  tb, 0, stream>>>(w_v,   wqkvT + 2048*1024, 1024, 1024, 1.f);
    k_transpose_cvt<<<dim3(32, 32),  tb, 0, stream>>>(w_o,   woT,               1024, 1024, 1.f);
    k_transpose_cvt<<<dim3(128, 32), tb, 0, stream>>>(w_fc1, wfc1T,             1024, 4096, 1.f);
    k_transpose_cvt<<<dim3(32, 128), tb, 0, stream>>>(w_fc2, wfc2T,             4096, 1024, 1.f);

    k_layernorm<<<NR, 256, 0, stream>>>(x, ln1_g, ln1_b, h1);
    k_gemm<<<dim3(3072/128, NR/128), 256, 0, stream>>>(h1, wqkvT, NR, 3072, 1024,
                                                       nullptr, nullptr, nullptr, qkv, 0,
                                                       nullptr, 1);
    k_vtrans<<<dim3(Tz/64, Bz*Hz), 256, 0, stream>>>(qkv, Vt);
    k_attn<<<dim3(32, Hz, Bz), 256, 0, stream>>>(qkv, Vt, ctx);

    // out-proj: split-K=2, f32 partials in g; fused reduce + LN2 -> y, h2
    k_gemm<<<dim3(1024/128, NR/128, 2), 256, 0, stream>>>(ctx, woT, NR, 1024, 1024,
                                                          nullptr, nullptr, nullptr, nullptr, 0,
                                                          projPart, 2);
    k_reduce_ln<<<NR, 256, 0, stream>>>(projPart, MN, b_o, x, y, ln2_g, ln2_b, h2);

    k_gemm<<<dim3(4096/128, NR/128), 256, 0, stream>>>(h2, wfc1T, NR, 4096, 1024,
                                                       b_fc1, nullptr, nullptr, g, 1,
                                                       nullptr, 1);
    // FC2: split-K=2, f32 partials in h1+qkv; reduce fuses +b_fc2 +y -> out (f32)
    k_gemm<<<dim3(1024/128, NR/128, 2), 256, 0, stream>>>(g, wfc2T, NR, 1024, 4096,
                                                          nullptr, nullptr, nullptr, nullptr, 0,
                                                          fc2Part, 2);
    k_reduce_out<<<MN / 1024, 256, 0, stream>>>(fc2Part, MN, 1024, b_fc2, y, out);
    (void)in_sizes; (void)n_in; (void)out_size; (void)ws_size;
}

// Round 8
// 386.105 us; speedup vs baseline: 1.1033x; 1.0537x over previous
//
#include <hip/hip_runtime.h>
#include <hip/hip_bf16.h>
#include <cstdint>

#define Bz 2
#define Tz 2048
#define Dz 1024
#define Hz 16
#define NR (Bz*Tz)   // 4096 rows

typedef __bf16 bf16;
typedef __bf16 bf16x8 __attribute__((ext_vector_type(8)));
typedef __bf16 bf16x4 __attribute__((ext_vector_type(4)));
typedef short  s16x4  __attribute__((ext_vector_type(4)));
typedef float  f32x4  __attribute__((ext_vector_type(4)));

typedef unsigned int u32as1 __attribute__((address_space(1)));
typedef unsigned int u32as3 __attribute__((address_space(3)));

__device__ __forceinline__ void gl2lds16(const void* gp, void* lp) {
    __builtin_amdgcn_global_load_lds((u32as1*)gp, (u32as3*)lp, 16, 0, 0);
}

// ---------------- transpose + f32->bf16 cast (+scale): W[K][N] -> WT[N][K] ----------------
__global__ void k_transpose_cvt(const float* __restrict__ W, bf16* __restrict__ WT,
                                int K, int N, float scale) {
    __shared__ float tile[32][33];
    const int n0 = blockIdx.x * 32, k0 = blockIdx.y * 32;
    const int tx = threadIdx.x, ty = threadIdx.y;   // (32,8)
#pragma unroll
    for (int i = 0; i < 4; i++)
        tile[ty + i*8][tx] = W[(size_t)(k0 + ty + i*8) * N + n0 + tx];
    __syncthreads();
#pragma unroll
    for (int i = 0; i < 4; i++)
        WT[(size_t)(n0 + ty + i*8) * K + k0 + tx] = (bf16)(tile[tx][ty + i*8] * scale);
}

// ---------------- V transpose: qkv V-third -> Vt[(b*16+h)*64 + v][Tz] ----------------
__global__ void k_vtrans(const bf16* __restrict__ qkv, bf16* __restrict__ Vt) {
    __shared__ bf16 tile[64][72];   // [t_local][v], padded
    const int t0 = blockIdx.x * 64;
    const int bh = blockIdx.y;
    const int b = bh >> 4, h = bh & 15;
    const int tid = threadIdx.x;
    const int tr = tid >> 3, c8 = (tid & 7) * 8;
    const bf16* src = qkv + (size_t)b * Tz * 3072 + 2048 + h * 64;
#pragma unroll
    for (int i = 0; i < 2; i++) {
        bf16x8 v = *(const bf16x8*)(src + (size_t)(t0 + i*32 + tr) * 3072 + c8);
        *(bf16x8*)&tile[i*32 + tr][c8] = v;
    }
    __syncthreads();
    bf16* dst = Vt + (size_t)bh * 64 * Tz + t0;
#pragma unroll
    for (int i = 0; i < 2; i++) {
        const int vr = i*32 + tr;
        bf16x8 o;
#pragma unroll
        for (int j = 0; j < 8; j++) o[j] = tile[c8 + j][vr];
        *(bf16x8*)(dst + (size_t)vr * Tz + c8) = o;
    }
}

// ---------------- LayerNorm (ddof=1 std, eps added to std) -> bf16 ----------------
__global__ void k_layernorm(const float* __restrict__ X, const float* __restrict__ gam,
                            const float* __restrict__ bet, bf16* __restrict__ out) {
    const int row = blockIdx.x, t = threadIdx.x;   // 256 threads, D=1024
    const float4 v = ((const float4*)(X + (size_t)row * Dz))[t];
    float s  = v.x + v.y + v.z + v.w;
    float ss = v.x*v.x + v.y*v.y + v.z*v.z + v.w*v.w;
#pragma unroll
    for (int o = 1; o < 64; o <<= 1) { s += __shfl_xor(s, o); ss += __shfl_xor(ss, o); }
    __shared__ float rs[4], rss[4];
    if ((t & 63) == 0) { rs[t >> 6] = s; rss[t >> 6] = ss; }
    __syncthreads();
    s  = rs[0] + rs[1] + rs[2] + rs[3];
    ss = rss[0] + rss[1] + rss[2] + rss[3];
    const float mean = s * (1.f / Dz);
    const float var  = fmaxf((ss - s * mean) * (1.f / (Dz - 1)), 0.f);
    const float inv  = 1.f / (sqrtf(var) + 1e-6f);
    const float4 gv = ((const float4*)gam)[t];
    const float4 bv = ((const float4*)bet)[t];
    bf16x4 o;
    o[0] = (bf16)((v.x - mean) * gv.x * inv + bv.x);
    o[1] = (bf16)((v.y - mean) * gv.y * inv + bv.y);
    o[2] = (bf16)((v.z - mean) * gv.z * inv + bv.z);
    o[3] = (bf16)((v.w - mean) * gv.w * inv + bv.w);
    *(bf16x4*)(out + (size_t)row * Dz + t * 4) = o;
}

// ---------------- generic bf16 GEMM, double-buffered K-loop ----------------
// Raw s_barrier + manual vmcnt(8): next tile's global_load_lds stay in flight
// across the barriers (never drain to 0 mid-loop) — AITER-style pipelining.
__global__ __launch_bounds__(256) void k_gemm(
    const bf16* __restrict__ A, const bf16* __restrict__ BT,
    int M, int N, int K,
    const float* __restrict__ bias, const float* __restrict__ resid,
    float* __restrict__ Cf, bf16* __restrict__ Cb, int act,
    float* __restrict__ Pf, int nsplit)
{
    __shared__ bf16 lA[2][128 * 64];
    __shared__ bf16 lB[2][128 * 64];
    const int tid = threadIdx.x;
    const int w = tid >> 6, lane = tid & 63;
    const int q = lane >> 4, l16 = lane & 15;
    const int m0 = blockIdx.y * 128, n0 = blockIdx.x * 128;
    const int wm = (w >> 1) * 64, wn = (w & 1) * 64;

    const int srow = lane >> 3;                 // 0..7
    const int skg  = (lane & 7) ^ srow;         // XOR-swizzled k-slot
    const bf16* Ab = A  + (size_t)(m0 + w * 32 + srow) * K + skg * 8;
    const bf16* Bb = BT + (size_t)(n0 + w * 32 + srow) * K + skg * 8;

    f32x4 acc[4][4] = {};

    const int kPer  = K / nsplit;
    const int kBeg  = blockIdx.z * kPer;
    const int iters = kPer >> 6;

    // prologue: stage buf0
#pragma unroll
    for (int i = 0; i < 4; i++) {
        gl2lds16(Ab + (size_t)i * 8 * K + kBeg, &lA[0][0] + w * 2048 + i * 512);
        gl2lds16(Bb + (size_t)i * 8 * K + kBeg, &lB[0][0] + w * 2048 + i * 512);
    }

    for (int it = 0; it < iters; ++it) {
        const int cur = it & 1;
        asm volatile("s_barrier" ::: "memory");
        if (it + 1 < iters) {
            const int k0 = kBeg + (it + 1) * 64;
#pragma unroll
            for (int i = 0; i < 4; i++) {
                gl2lds16(Ab + (size_t)i * 8 * K + k0, &lA[cur ^ 1][0] + w * 2048 + i * 512);
                gl2lds16(Bb + (size_t)i * 8 * K + k0, &lB[cur ^ 1][0] + w * 2048 + i * 512);
            }
            asm volatile("s_waitcnt vmcnt(8)" ::: "memory");   // own buf[cur] loads landed
        } else {
            asm volatile("s_waitcnt vmcnt(0)" ::: "memory");
        }
        asm volatile("s_barrier" ::: "memory");                // everyone's buf[cur] landed

        const bf16* lAc = lA[cur];
        const bf16* lBc = lB[cur];
#pragma unroll
        for (int kh = 0; kh < 2; kh++) {
            const int sl = (((kh * 4 + q) ^ (l16 & 7)) * 8);
            bf16x8 af[4], bfr[4];
#pragma unroll
            for (int t = 0; t < 4; t++) {
                af[t]  = *(const bf16x8*)(lAc + (wm + t * 16 + l16) * 64 + sl);
                bfr[t] = *(const bf16x8*)(lBc + (wn + t * 16 + l16) * 64 + sl);
            }
#pragma unroll
            for (int i = 0; i < 4; i++)
#pragma unroll
                for (int j = 0; j < 4; j++)
                    acc[i][j] = __builtin_amdgcn_mfma_f32_16x16x32_bf16(
                        af[i], bfr[j], acc[i][j], 0, 0, 0);
        }
    }

    if (nsplit > 1) {
        float* P = Pf + (size_t)blockIdx.z * M * N;
#pragma unroll
        for (int i = 0; i < 4; i++) {
            const int gr = m0 + wm + i * 16 + q * 4;
#pragma unroll
            for (int j = 0; j < 4; j++) {
                const int gc = n0 + wn + j * 16 + l16;
#pragma unroll
                for (int r = 0; r < 4; r++)
                    P[(size_t)(gr + r) * N + gc] = acc[i][j][r];
            }
        }
        return;
    }

#pragma unroll
    for (int i = 0; i < 4; i++) {
        const int gr = m0 + wm + i * 16 + q * 4;
#pragma unroll
        for (int j = 0; j < 4; j++) {
            const int gc = n0 + wn + j * 16 + l16;
            const float bv = bias ? bias[gc] : 0.f;
#pragma unroll
            for (int r = 0; r < 4; r++) {
                float v = acc[i][j][r] + bv;
                if (act) v = 0.5f * v * (1.f + erff(v * 0.70710678118f));
                const size_t idx = (size_t)(gr + r) * N + gc;
                if (resid) v += resid[idx];
                if (Cf) Cf[idx] = v;
                else    Cb[idx] = (bf16)v;
            }
        }
    }
}

// ---------------- proj reduce (2 f32 partials) + bias + resid -> y, then LN2 -> h2 ----------------
__global__ __launch_bounds__(256) void k_reduce_ln(
    const float* __restrict__ part, size_t MN,
    const float* __restrict__ bias, const float* __restrict__ resid,
    float* __restrict__ y,
    const float* __restrict__ gam, const float* __restrict__ bet,
    bf16* __restrict__ h2)
{
    const int row = blockIdx.x, t = threadIdx.x;
    const size_t i4 = (size_t)row * Dz + t * 4;
    float4 v = *(const float4*)(part + i4);
    const float4 p1 = *(const float4*)(part + MN + i4);
    const float4 bv = ((const float4*)bias)[t];
    const float4 rv = *(const float4*)(resid + i4);
    v.x += p1.x + bv.x + rv.x; v.y += p1.y + bv.y + rv.y;
    v.z += p1.z + bv.z + rv.z; v.w += p1.w + bv.w + rv.w;
    *(float4*)(y + i4) = v;

    float s  = v.x + v.y + v.z + v.w;
    float ss = v.x*v.x + v.y*v.y + v.z*v.z + v.w*v.w;
#pragma unroll
    for (int o = 1; o < 64; o <<= 1) { s += __shfl_xor(s, o); ss += __shfl_xor(ss, o); }
    __shared__ float rs[4], rss[4];
    if ((t & 63) == 0) { rs[t >> 6] = s; rss[t >> 6] = ss; }
    __syncthreads();
    s  = rs[0] + rs[1] + rs[2] + rs[3];
    ss = rss[0] + rss[1] + rss[2] + rss[3];
    const float mean = s * (1.f / Dz);
    const float var  = fmaxf((ss - s * mean) * (1.f / (Dz - 1)), 0.f);
    const float inv  = 1.f / (sqrtf(var) + 1e-6f);
    const float4 gv = ((const float4*)gam)[t];
    const float4 be = ((const float4*)bet)[t];
    bf16x4 o;
    o[0] = (bf16)((v.x - mean) * gv.x * inv + be.x);
    o[1] = (bf16)((v.y - mean) * gv.y * inv + be.y);
    o[2] = (bf16)((v.z - mean) * gv.z * inv + be.z);
    o[3] = (bf16)((v.w - mean) * gv.w * inv + be.w);
    *(bf16x4*)(h2 + i4) = o;
}

// ---------------- final reduce (2 f32 partials) + bias + resid -> out (f32) ----------------
__global__ __launch_bounds__(256) void k_reduce_out(
    const float* __restrict__ part, size_t MN, int N,
    const float* __restrict__ bias, const float* __restrict__ resid,
    float* __restrict__ out)
{
    const size_t i4 = ((size_t)blockIdx.x * 256 + threadIdx.x) * 4;
    float4 v = *(const float4*)(part + i4);
    const float4 p1 = *(const float4*)(part + MN + i4);
    const int col = (int)(i4 % N);
    const float4 bv = *(const float4*)(bias + col);
    const float4 rv = *(const float4*)(resid + i4);
    v.x += p1.x + bv.x + rv.x; v.y += p1.y + bv.y + rv.y;
    v.z += p1.z + bv.z + rv.z; v.w += p1.w + bv.w + rv.w;
    *(float4*)(out + i4) = v;
}

// ---------------- flash attention v5: balanced pairing + XCD-aware swizzle ----------------
// 1D grid of 1024 blocks: bh = blockIdx.x & 31 (fastest), pr = blockIdx.x >> 5.
// Under round-robin dispatch, all 32 pr-blocks of one (b,h) share indices mod 32
// -> same XCD -> K/V (512 KB) stays L2-resident per XCD; each XCD serves only
// 4 bh pairs (2 MB < 4 MB L2). Pure locality heuristic; correctness unaffected.
__global__ __launch_bounds__(256) void k_attn(const bf16* __restrict__ qkv,
                                              const bf16* __restrict__ Vt,
                                              bf16* __restrict__ ctx)
{
    __shared__ __align__(16) char smem[34816];
    bf16* lK = (bf16*)smem;             // [128 rows][64 elems]
    bf16* lV = (bf16*)(smem + 16384);   // [64 rows][128 elems]
    f32x4* sAcc = (f32x4*)smem;         // [wq][vt][lane]  (aliases lK)
    float*  sM  = (float*)(smem + 32768);
    float*  sL  = (float*)(smem + 33792);

    const int tid = threadIdx.x, lane = tid & 63, w = tid >> 6;
    const int l16 = lane & 15, quad = lane >> 4;
    const int wq = w & 1, ws = w >> 1;
    const int bh = blockIdx.x & 31;              // fastest -> fixes XCD
    const int pr = blockIdx.x >> 5;              // pair index 0..31
    const int b = bh >> 4, h = bh & 15;

    const bf16* Qp  = qkv + (size_t)b * Tz * 3072 + h * 64;
    const bf16* Kp  = Qp + 1024;
    const bf16* Vtp = Vt + (size_t)(b * Hz + h) * 64 * Tz;

    const int krow  = tid >> 3;
    const int kslot = (tid & 7) ^ (krow & 7);
    const bf16* Kg = Kp + (size_t)krow * 3072 + kslot * 8;
    const int vrow  = tid >> 4;
    const int vslot = (tid & 15) ^ (vrow & 7);
    const bf16* Vg = Vtp + (size_t)vrow * Tz + vslot * 8;

#pragma unroll
    for (int ti = 0; ti < 2; ti++) {
        const int t = ti ? (63 - pr) : pr;       // 32-row q-tile index
        const int q0 = t * 32 + wq * 16;         // this wave's 16 q rows

        bf16x8 qf[2];
#pragma unroll
        for (int kh = 0; kh < 2; kh++)
            qf[kh] = *(const bf16x8*)(Qp + (size_t)(q0 + l16) * 3072 + kh*32 + quad*8);

        f32x4 acc[4] = {};
        float m = -1e30f, l = 0.f;

        const int keyEnd = t * 32 + 32;
        for (int ktB = 0; ktB < keyEnd; ktB += 128) {
            __syncthreads();                     // staging vs prior compute/merge
#pragma unroll
            for (int s = 0; s < 4; s++) {
                gl2lds16(Kg + (size_t)(ktB + s * 32) * 3072, lK + s * 2048 + w * 512);
                gl2lds16(Vg + (size_t)s * 16 * Tz + ktB,     lV + s * 2048 + w * 512);
            }
            __syncthreads();

            const int kt = ktB + ws * 64;
            if (kt <= q0 + 15) {                 // wave-uniform causal skip
                f32x4 sv[4];
                const int sw = l16 & 7;
#pragma unroll
                for (int c = 0; c < 4; c++) {
                    const int R = ws * 64 + c * 16 + l16;
                    bf16x8 kf0 = *(const bf16x8*)(lK + R * 64 + ((quad     ^ sw) * 8));
                    bf16x8 kf1 = *(const bf16x8*)(lK + R * 64 + (((4+quad) ^ sw) * 8));
                    f32x4 z = {0.f, 0.f, 0.f, 0.f};
                    z = __builtin_amdgcn_mfma_f32_16x16x32_bf16(kf0, qf[0], z, 0, 0, 0);
                    z = __builtin_amdgcn_mfma_f32_16x16x32_bf16(kf1, qf[1], z, 0, 0, 0);
                    sv[c] = z;
                }
                if (kt + 63 > q0) {              // mask only on diagonal tiles
#pragma unroll
                    for (int c = 0; c < 4; c++)
#pragma unroll
                        for (int r = 0; r < 4; r++)
                            if (kt + c*16 + quad*4 + r > q0 + l16) sv[c][r] = -1e30f;
                }
                float t0 = fmaxf(fmaxf(sv[0][0], sv[0][1]), fmaxf(sv[0][2], sv[0][3]));
                float t1 = fmaxf(fmaxf(sv[1][0], sv[1][1]), fmaxf(sv[1][2], sv[1][3]));
                float t2 = fmaxf(fmaxf(sv[2][0], sv[2][1]), fmaxf(sv[2][2], sv[2][3]));
                float t3 = fmaxf(fmaxf(sv[3][0], sv[3][1]), fmaxf(sv[3][2], sv[3][3]));
                float tm = fmaxf(fmaxf(t0, t1), fmaxf(t2, t3));
                tm = fmaxf(tm, __shfl_xor(tm, 16));
                tm = fmaxf(tm, __shfl_xor(tm, 32));
                if (__any(tm > m)) {
                    const float mn = fmaxf(m, tm);
                    const float a  = __expf(m - mn);
                    m = mn;
                    l *= a;
#pragma unroll
                    for (int vt = 0; vt < 4; vt++)
#pragma unroll
                        for (int r = 0; r < 4; r++) acc[vt][r] *= a;
                }
                float ts = 0.f;
#pragma unroll
                for (int c = 0; c < 4; c++) {
                    s16x4 vf[4];
                    const int gslot = ws * 8 + c * 2 + (quad >> 1);
#pragma unroll
                    for (int vt = 0; vt < 4; vt++) {
                        const int Rv = vt * 16 + l16;
                        vf[vt] = *(const s16x4*)(lV + Rv * 128 + ((gslot ^ (Rv & 7)) * 8)
                                                 + (quad & 1) * 4);
                    }
                    bf16x4 tb;
#pragma unroll
                    for (int r = 0; r < 4; r++) {
                        const float p = __expf(sv[c][r] - m);
                        ts += p;
                        tb[r] = (bf16)p;
                    }
                    const s16x4 pb = __builtin_bit_cast(s16x4, tb);
#pragma unroll
                    for (int vt = 0; vt < 4; vt++)
                        acc[vt] = __builtin_amdgcn_mfma_f32_16x16x16bf16_1k(
                            vf[vt], pb, acc[vt], 0, 0, 0);
                }
                ts += __shfl_xor(ts, 16);
                ts += __shfl_xor(ts, 32);
                l += ts;
            }
        }

        // merge ws halves (LDS aliased onto staging buffers)
        __syncthreads();
        if (ws == 1) {
            sM[wq * 64 + lane] = m;
            sL[wq * 64 + lane] = l;
#pragma unroll
            for (int vt = 0; vt < 4; vt++)
                sAcc[(wq * 4 + vt) * 64 + lane] = acc[vt];
        }
        __syncthreads();
        if (ws == 0) {
            const float m1 = sM[wq * 64 + lane], l1 = sL[wq * 64 + lane];
            const float M  = fmaxf(m, m1);
            const float a0 = __expf(m - M), a1 = __expf(m1 - M);
            const float inv = 1.f / (l * a0 + l1 * a1);
#pragma unroll
            for (int vt = 0; vt < 4; vt++) {
                const f32x4 o1 = sAcc[(wq * 4 + vt) * 64 + lane];
                bf16x4 o;
#pragma unroll
                for (int r = 0; r < 4; r++)
                    o[r] = (bf16)((acc[vt][r] * a0 + o1[r] * a1) * inv);
                *(bf16x4*)(ctx + (size_t)(b * Tz + q0 + l16) * 1024
                           + h * 64 + vt * 16 + quad * 4) = o;
            }
        }
    }
}

// ---------------- driver ----------------
extern "C" void kernel_launch(void* const* d_in, const int* in_sizes, int n_in,
                              void* d_out, int out_size, void* d_ws, size_t ws_size,
                              hipStream_t stream)
{
    const float* x     = (const float*)d_in[0];
    const float* w_q   = (const float*)d_in[1];
    const float* w_k   = (const float*)d_in[2];
    const float* w_v   = (const float*)d_in[3];
    const float* w_o   = (const float*)d_in[4];
    const float* b_o   = (const float*)d_in[5];
    const float* w_fc1 = (const float*)d_in[6];
    const float* b_fc1 = (const float*)d_in[7];
    const float* w_fc2 = (const float*)d_in[8];
    const float* b_fc2 = (const float*)d_in[9];
    const float* ln1_g = (const float*)d_in[10];
    const float* ln1_b = (const float*)d_in[11];
    const float* ln2_g = (const float*)d_in[12];
    const float* ln2_b = (const float*)d_in[13];
    float* out = (float*)d_out;

    char* p = (char*)d_ws;
    bf16* wqkvT = (bf16*)p; p += (size_t)3072 * 1024 * 2;
    bf16* woT   = (bf16*)p; p += (size_t)1024 * 1024 * 2;
    bf16* wfc1T = (bf16*)p; p += (size_t)4096 * 1024 * 2;
    bf16* wfc2T = (bf16*)p; p += (size_t)1024 * 4096 * 2;
    bf16* h1    = (bf16*)p; p += (size_t)NR * 1024 * 2;   // reused: Vt, then FC2 partials
    bf16* qkv   = (bf16*)p; p += (size_t)NR * 3072 * 2;   // FC2 partials tail
    bf16* ctx   = (bf16*)p; p += (size_t)NR * 1024 * 2;
    float* y    = (float*)p; p += (size_t)NR * 1024 * 4;
    bf16* h2    = (bf16*)p; p += (size_t)NR * 1024 * 2;
    bf16* g     = (bf16*)p; p += (size_t)NR * 4096 * 2;   // reused: proj partials
    bf16* Vt    = h1;
    float* projPart = (float*)g;    // 2 * NR*1024*4 B = 33.55 MB == sizeof(g)
    float* fc2Part  = (float*)h1;   // 33.55 MB == sizeof(h1)+sizeof(qkv)
    const size_t MN = (size_t)NR * 1024;

    const dim3 tb(32, 8);
    k_transpose_cvt<<<dim3(32, 32),  tb, 0, stream>>>(w_q,   wqkvT,             1024, 1024, 0.125f);
    k_transpose_cvt<<<dim3(32, 32),  tb, 0, stream>>>(w_k,   wqkvT + 1024*1024, 1024, 1024, 1.f);
    k_transpose_cvt<<<dim3(32, 32),  tb, 0, stream>>>(w_v,   wqkvT + 2048*1024, 1024, 1024, 1.f);
    k_transpose_cvt<<<dim3(32, 32),  tb, 0, stream>>>(w_o,   woT,               1024, 1024, 1.f);
    k_transpose_cvt<<<dim3(128, 32), tb, 0, stream>>>(w_fc1, wfc1T,             1024, 4096, 1.f);
    k_transpose_cvt<<<dim3(32, 128), tb, 0, stream>>>(w_fc2, wfc2T,             4096, 1024, 1.f);

    k_layernorm<<<NR, 256, 0, stream>>>(x, ln1_g, ln1_b, h1);
    k_gemm<<<dim3(3072/128, NR/128), 256, 0, stream>>>(h1, wqkvT, NR, 3072, 1024,
                                                       nullptr, nullptr, nullptr, qkv, 0,
                                                       nullptr, 1);
    k_vtrans<<<dim3(Tz/64, Bz*Hz), 256, 0, stream>>>(qkv, Vt);
    k_attn<<<dim3(32 * Hz * Bz), 256, 0, stream>>>(qkv, Vt, ctx);

    // out-proj: split-K=2, f32 partials in g; fused reduce + LN2 -> y, h2
    k_gemm<<<dim3(1024/128, NR/128, 2), 256, 0, stream>>>(ctx, woT, NR, 1024, 1024,
                                                          nullptr, nullptr, nullptr, nullptr, 0,
                                                          projPart, 2);
    k_reduce_ln<<<NR, 256, 0, stream>>>(projPart, MN, b_o, x, y, ln2_g, ln2_b, h2);

    k_gemm<<<dim3(4096/128, NR/128), 256, 0, stream>>>(h2, wfc1T, NR, 4096, 1024,
                                                       b_fc1, nullptr, nullptr, g, 1,
                                                       nullptr, 1);
    // FC2: split-K=2, f32 partials in h1+qkv; reduce fuses +b_fc2 +y -> out (f32)
    k_gemm<<<dim3(1024/128, NR/128, 2), 256, 0, stream>>>(g, wfc2T, NR, 1024, 4096,
                                                          nullptr, nullptr, nullptr, nullptr, 0,
                                                          fc2Part, 2);
    k_reduce_out<<<MN / 1024, 256, 0, stream>>>(fc2Part, MN, 1024, b_fc2, y, out);
    (void)in_sizes; (void)n_in; (void)out_size; (void)ws_size;
}